// Round 8
// baseline (1617.345 us; speedup 1.0000x reference)
//
#include <hip/hip_runtime.h>
#include <hip/hip_fp16.h>
#include <stdint.h>

#define T_STEPS 1024
#define HDIM    128
#define NT      512

// K-sliced, single-barrier pipelined design (R8 = R7 + forced 256 arch VGPRs):
//   wave w = tid>>6 (0..7), lane l = tid&63
//   slice   s = l & 3        -> h columns [32s, 32s+32)
//   element e = 16w + (l>>2) (0..127)
// Iteration k fuses: gates1(k)   = W_hh1*h1(k-1)            (+ x(k), bias)
//                    gates2(k-1) = W_ih2*h1(k-1) + W_hh2*h2(k-2)
// One 192-dot block (8 indep acc chains), two epilogues, ONE barrier.
//
// R7 lesson: at NT=512 the allocator splits the 256-reg unified budget
// 128 arch + 128 accum and parks the pinned weights in AGPRs -> every
// dot2 pays a v_accvgpr_read (~1650 cyc/SIMD/step, the dominant cost;
// VGPR_Count=128 with zero scratch traffic is the signature).
// amdgpu_num_vgpr(256) overrides the split heuristic directly.

#if __has_attribute(amdgpu_num_vgpr)
#define NUMVGPR __attribute__((amdgpu_num_vgpr(256)))
#else
#define NUMVGPR
#endif

typedef _Float16 v2h __attribute__((ext_vector_type(2)));
union HU { uint32_t u; v2h v; };

__device__ __forceinline__ float dot2h(uint32_t a, uint32_t b, float c) {
    HU ua, ub; ua.u = a; ub.u = b;
    return __builtin_amdgcn_fdot2(ua.v, ub.v, c, false);  // v_dot2_f32_f16
}
__device__ __forceinline__ uint32_t packh2f(float2 e) {
    return (uint32_t)__half_as_ushort(__float2half_rn(e.x)) |
           ((uint32_t)__half_as_ushort(__float2half_rn(e.y)) << 16);
}
__device__ __forceinline__ uint16_t f2h(float f) {
    return __half_as_ushort(__float2half_rn(f));
}
// act(a,1)=sigmoid(a); act(a,2)=tanh(a)
__device__ __forceinline__ float actf(float a, float m) {
    return 1.0f - m * __builtin_amdgcn_rcpf(__expf(m * a) + 1.0f);
}
// reduce over the 4 slice-lanes (lane bits 0..1): two DPP quad-perm adds.
__device__ __forceinline__ float red2(float v) {
    int iv = __float_as_int(v);
    v += __int_as_float(__builtin_amdgcn_update_dpp(0, iv, 0xB1, 0xF, 0xF, true)); // xor1
    iv = __float_as_int(v);
    v += __int_as_float(__builtin_amdgcn_update_dpp(0, iv, 0x4E, 0xF, 0xF, true)); // xor2
    return v;
}

#define SB() __builtin_amdgcn_sched_barrier(0)
#define PIN4(W) asm volatile("" : "+v"(W.x), "+v"(W.y), "+v"(W.z), "+v"(W.w))

// pack 32 consecutive floats at P into 4 uint4 of f16 pairs
#define SETW16(Wa, Wb, Wc, Wd, P) do { const float2* _r = (const float2*)(P); \
    Wa = make_uint4(packh2f(_r[0]),  packh2f(_r[1]),                       \
                    packh2f(_r[2]),  packh2f(_r[3]));                      \
    Wb = make_uint4(packh2f(_r[4]),  packh2f(_r[5]),                       \
                    packh2f(_r[6]),  packh2f(_r[7]));                      \
    Wc = make_uint4(packh2f(_r[8]),  packh2f(_r[9]),                       \
                    packh2f(_r[10]), packh2f(_r[11]));                     \
    Wd = make_uint4(packh2f(_r[12]), packh2f(_r[13]),                      \
                    packh2f(_r[14]), packh2f(_r[15])); } while (0)

// row pack + immediate pin + scheduling fence: caps init pressure spike.
#define ROW(Wa, Wb, Wc, Wd, P) do {                                        \
    SETW16(Wa, Wb, Wc, Wd, P);                                             \
    PIN4(Wa); PIN4(Wb); PIN4(Wc); PIN4(Wd); SB(); } while (0)

// 8 dot2s: one weight pair (2 uint4 = 16 cols) vs h pair
#define DOT8(Wa, Wb, H0, H1, acc) do {                                     \
    acc = dot2h(Wa.x, H0.x, acc); acc = dot2h(Wa.y, H0.y, acc);            \
    acc = dot2h(Wa.z, H0.z, acc); acc = dot2h(Wa.w, H0.w, acc);            \
    acc = dot2h(Wb.x, H1.x, acc); acc = dot2h(Wb.y, H1.y, acc);            \
    acc = dot2h(Wb.z, H1.z, acc); acc = dot2h(Wb.w, H1.w, acc); } while (0)

__global__ __launch_bounds__(NT)
__attribute__((amdgpu_waves_per_eu(2, 2)))
NUMVGPR
void lstm_persistent(
    const float* __restrict__ x,
    const float* __restrict__ W_ih1, const float* __restrict__ W_hh1,
    const float* __restrict__ b_ih1, const float* __restrict__ b_hh1,
    const float* __restrict__ W_ih2, const float* __restrict__ W_hh2,
    const float* __restrict__ b_ih2, const float* __restrict__ b_hh2,
    const float* __restrict__ W_out, const float* __restrict__ b_out,
    float* __restrict__ out)
{
    const int b   = blockIdx.x;
    const int tid = threadIdx.x;
    const int w   = tid >> 6;
    const int l   = tid & 63;
    const int s   = l & 3;
    const int e   = (w << 4) | (l >> 2);
    const int co  = s << 5;                       // column offset (floats)

    __shared__ __align__(16) uint32_t h1p[2][HDIM / 2];   // h1 f16 pairs, dbuf
    __shared__ __align__(16) uint32_t h2p[2][HDIM / 2];   // h2 f16 pairs, dbuf
    __shared__ __align__(16) float4 bct1[HDIM];   // per-element L1 biases (i,f,g,o)
    __shared__ __align__(16) float4 bctw[HDIM];   // per-element W_ih1    (i,f,g,o)
    __shared__ __align__(16) float4 bct2[HDIM];   // per-element L2 biases
    __shared__ float pbuf[2][8];                  // per-wave out partials, dbuf

    // ---- one-time: weight slices -> 48 named uint4 (192 VGPRs), fenced
    uint4 m1_00,m1_01,m1_02,m1_03, m1_10,m1_11,m1_12,m1_13;   // W_hh1
    uint4 m1_20,m1_21,m1_22,m1_23, m1_30,m1_31,m1_32,m1_33;
    uint4 m2_00,m2_01,m2_02,m2_03, m2_10,m2_11,m2_12,m2_13;   // W_ih2
    uint4 m2_20,m2_21,m2_22,m2_23, m2_30,m2_31,m2_32,m2_33;
    uint4 m3_00,m3_01,m3_02,m3_03, m3_10,m3_11,m3_12,m3_13;   // W_hh2
    uint4 m3_20,m3_21,m3_22,m3_23, m3_30,m3_31,m3_32,m3_33;
    {
        const float* p = W_hh1 + e * HDIM + co;
        ROW(m1_00,m1_01,m1_02,m1_03, p);
        ROW(m1_10,m1_11,m1_12,m1_13, p + 128 * HDIM);
        ROW(m1_20,m1_21,m1_22,m1_23, p + 256 * HDIM);
        ROW(m1_30,m1_31,m1_32,m1_33, p + 384 * HDIM);
        p = W_ih2 + e * HDIM + co;
        ROW(m2_00,m2_01,m2_02,m2_03, p);
        ROW(m2_10,m2_11,m2_12,m2_13, p + 128 * HDIM);
        ROW(m2_20,m2_21,m2_22,m2_23, p + 256 * HDIM);
        ROW(m2_30,m2_31,m2_32,m2_33, p + 384 * HDIM);
        p = W_hh2 + e * HDIM + co;
        ROW(m3_00,m3_01,m3_02,m3_03, p);
        ROW(m3_10,m3_11,m3_12,m3_13, p + 128 * HDIM);
        ROW(m3_20,m3_21,m3_22,m3_23, p + 256 * HDIM);
        ROW(m3_30,m3_31,m3_32,m3_33, p + 384 * HDIM);
    }

    // ---- one-time: bias / x-weight tables in LDS
    if (tid < HDIM) {
        bct1[tid] = make_float4(
            b_ih1[tid]       + b_hh1[tid],
            b_ih1[tid + 128] + b_hh1[tid + 128],
            b_ih1[tid + 256] + b_hh1[tid + 256],
            b_ih1[tid + 384] + b_hh1[tid + 384]);
        bctw[tid] = make_float4(W_ih1[tid], W_ih1[tid + 128],
                                W_ih1[tid + 256], W_ih1[tid + 384]);
        bct2[tid] = make_float4(
            b_ih2[tid]       + b_hh2[tid],
            b_ih2[tid + 128] + b_hh2[tid + 128],
            b_ih2[tid + 256] + b_hh2[tid + 256],
            b_ih2[tid + 384] + b_hh2[tid + 384]);
    }
    const float wo = (s == 0) ? W_out[e] : 0.0f;
    const float bo = b_out[0];

    float c1 = 0.f, c2 = 0.f;                      // replicated across 4 lanes

    if (tid < HDIM / 2) {
        h1p[0][tid] = 0u; h1p[1][tid] = 0u;        // h1(-1) = h2(-1) = 0
        h2p[0][tid] = 0u; h2p[1][tid] = 0u;
    }
    __syncthreads();

    const float* xb = x + b * T_STEPS;
    float*       ob = out + b * T_STEPS;
    float x_cur = xb[0];

    // Iteration k (k = 0..T): computes h1(k) and h2(k-1)/out(k-1).
    for (int k = 0; k <= T_STEPS; ++k) {
        const int rb = k & 1, wbuf = rb ^ 1;
        float x_nxt = xb[(k + 1 < T_STEPS) ? (k + 1) : (T_STEPS - 1)];

        // ---- store out(k-2): partials were published before last barrier
        if (k >= 2 && tid < 8) {
            float ssum = pbuf[wbuf][tid];
            ssum += __shfl_xor(ssum, 1, 64);
            ssum += __shfl_xor(ssum, 2, 64);
            ssum += __shfl_xor(ssum, 4, 64);
            if (tid == 0) ob[k - 2] = ssum + bo;
        }

        // ---- fused dot block: 192 dot2, 8 indep acc chains, phased H
        // loads (Ha/Hb now; Hc/Hd issued under the Hb dots) to cap peak
        // H-liveness at ~24 dwords -> total demand ~245 <= 256 arch.
        const uint4* H1 = (const uint4*)h1p[rb];
        const uint4* H2 = (const uint4*)h2p[rb];
        uint4 Ha0 = H1[4*s+0], Ha1 = H1[4*s+1];   // h1 cols [co, co+16)
        uint4 Hb0 = H1[4*s+2], Hb1 = H1[4*s+3];   // h1 cols [co+16, co+32)
        float a0=0.f,a1=0.f,a2=0.f,a3=0.f, q0=0.f,q1=0.f,q2=0.f,q3=0.f;
        // phase A: h1 first 16 cols -> m1 + m2 (8 chains)
        DOT8(m1_00,m1_01, Ha0,Ha1, a0); DOT8(m1_10,m1_11, Ha0,Ha1, a1);
        DOT8(m1_20,m1_21, Ha0,Ha1, a2); DOT8(m1_30,m1_31, Ha0,Ha1, a3);
        DOT8(m2_00,m2_01, Ha0,Ha1, q0); DOT8(m2_10,m2_11, Ha0,Ha1, q1);
        DOT8(m2_20,m2_21, Ha0,Ha1, q2); DOT8(m2_30,m2_31, Ha0,Ha1, q3);
        SB();
        // issue h2 reads; their ~120-cyc latency hides under phase B's dots
        uint4 Hc0 = H2[4*s+0], Hc1 = H2[4*s+1];
        uint4 Hd0 = H2[4*s+2], Hd1 = H2[4*s+3];
        // phase B: h1 second 16 cols
        DOT8(m1_02,m1_03, Hb0,Hb1, a0); DOT8(m1_12,m1_13, Hb0,Hb1, a1);
        DOT8(m1_22,m1_23, Hb0,Hb1, a2); DOT8(m1_32,m1_33, Hb0,Hb1, a3);
        DOT8(m2_02,m2_03, Hb0,Hb1, q0); DOT8(m2_12,m2_13, Hb0,Hb1, q1);
        DOT8(m2_22,m2_23, Hb0,Hb1, q2); DOT8(m2_32,m2_33, Hb0,Hb1, q3);
        SB();
        // phase C/D: h2 -> m3
        DOT8(m3_00,m3_01, Hc0,Hc1, q0); DOT8(m3_10,m3_11, Hc0,Hc1, q1);
        DOT8(m3_20,m3_21, Hc0,Hc1, q2); DOT8(m3_30,m3_31, Hc0,Hc1, q3);
        DOT8(m3_02,m3_03, Hd0,Hd1, q0); DOT8(m3_12,m3_13, Hd0,Hd1, q1);
        DOT8(m3_22,m3_23, Hd0,Hd1, q2); DOT8(m3_32,m3_33, Hd0,Hd1, q3);

        // ---- epilogue 1: h1(k)
        int ei = e;
        asm volatile("" : "+v"(ei));               // keep table reads in-loop
        float4 B1 = bct1[ei];
        float4 Wx = bctw[ei];
        a0 = red2(a0); a1 = red2(a1); a2 = red2(a2); a3 = red2(a3);
        float gi = actf(a0 + fmaf(x_cur, Wx.x, B1.x), 1.0f);
        float gf = actf(a1 + fmaf(x_cur, Wx.y, B1.y), 1.0f);
        float gg = actf(a2 + fmaf(x_cur, Wx.z, B1.z), 2.0f);
        float go = actf(a3 + fmaf(x_cur, Wx.w, B1.w), 1.0f);
        c1 = fmaf(gf, c1, gi * gg);
        float h1v = go * actf(c1, 2.0f);
        if (s == 0) ((uint16_t*)h1p[wbuf])[e] = f2h(h1v);

        // ---- epilogue 2: h2(k-1) + out(k-1) partial (skip at k=0)
        if (k > 0) {
            float4 B2 = bct2[ei];
            q0 = red2(q0); q1 = red2(q1); q2 = red2(q2); q3 = red2(q3);
            float hi = actf(q0 + B2.x, 1.0f);
            float hf = actf(q1 + B2.y, 1.0f);
            float hg = actf(q2 + B2.z, 2.0f);
            float ho = actf(q3 + B2.w, 1.0f);
            c2 = fmaf(hf, c2, hi * hg);
            float h2v = ho * actf(c2, 2.0f);
            if (s == 0) ((uint16_t*)h2p[wbuf])[e] = f2h(h2v);
            float part = wo * h2v;                 // wo==0 on s!=0 lanes
            part += __shfl_xor(part, 4,  64);
            part += __shfl_xor(part, 8,  64);
            part += __shfl_xor(part, 16, 64);
            part += __shfl_xor(part, 32, 64);
            if (l == 0) pbuf[rb][w] = part;
        }
        __syncthreads();   // single barrier: publish h1(k), h2(k-1), partials
        x_cur = x_nxt;
    }

    // ---- drain: out(T-1) partials were published at k=T
    if (tid < 8) {
        float ssum = pbuf[T_STEPS & 1][tid];
        ssum += __shfl_xor(ssum, 1, 64);
        ssum += __shfl_xor(ssum, 2, 64);
        ssum += __shfl_xor(ssum, 4, 64);
        if (tid == 0) ob[T_STEPS - 1] = ssum + bo;
    }
}

extern "C" void kernel_launch(void* const* d_in, const int* in_sizes, int n_in,
                              void* d_out, int out_size, void* d_ws, size_t ws_size,
                              hipStream_t stream) {
    const float* x     = (const float*)d_in[0];
    const float* W_ih1 = (const float*)d_in[1];
    const float* W_hh1 = (const float*)d_in[2];
    const float* b_ih1 = (const float*)d_in[3];
    const float* b_hh1 = (const float*)d_in[4];
    const float* W_ih2 = (const float*)d_in[5];
    const float* W_hh2 = (const float*)d_in[6];
    const float* b_ih2 = (const float*)d_in[7];
    const float* b_hh2 = (const float*)d_in[8];
    const float* W_out = (const float*)d_in[9];
    const float* b_out = (const float*)d_in[10];
    float* out = (float*)d_out;

    const int B = in_sizes[0] / T_STEPS;   // 256
    hipLaunchKernelGGL(lstm_persistent, dim3(B), dim3(NT), 0, stream,
                       x, W_ih1, W_hh1, b_ih1, b_hh1,
                       W_ih2, W_hh2, b_ih2, b_hh2, W_out, b_out, out);
}